// Round 18
// baseline (526.727 us; speedup 1.0000x reference)
//
#include <hip/hip_runtime.h>
#include <stdint.h>

#define H_DIM 1024
#define E_NUM 8
#define FF_DIM 4096
#define T_TOK 4096   // B*S = 2*2048

typedef __bf16 bf16x8 __attribute__((ext_vector_type(8)));
typedef float f32x4 __attribute__((ext_vector_type(4)));

#define AS1 __attribute__((address_space(1)))
#define AS3 __attribute__((address_space(3)))

__device__ __forceinline__ unsigned short f2bf(float f) {
  union { float f; uint32_t u; } v; v.f = f;
  uint32_t u = v.u;
  uint32_t r = u + 0x7fffu + ((u >> 16) & 1u);   // RNE
  return (unsigned short)(r >> 16);
}
__device__ __forceinline__ float bf2f(unsigned short u) {
  union { uint32_t u; float f; } v; v.u = ((uint32_t)u) << 16;
  return v.f;
}

// tanh-form GELU: max |err| vs exact-erf gelu ~1e-3 (budget: 5e-2 abs)
__device__ __forceinline__ float gelu_f(float x) {
  float s = x * x;
  float g = x * (1.5957691216f + 0.0713548162f * s);
  float t = __expf(-g);
  return x * __builtin_amdgcn_rcpf(1.0f + t);
}

// ---------------- gating (+ writes the shared-expert bf16 row: slot 8192+t
// needs no dispatch info, so gate emits it and gather covers routed slots only)
__global__ __launch_bounds__(64) void gate_kernel(
    const float* __restrict__ x, const float* __restrict__ gw, const float* __restrict__ gb,
    int* __restrict__ topidx, float* __restrict__ topw, int* __restrict__ counts,
    unsigned short* __restrict__ xg) {
  int t = blockIdx.x;
  int l = threadIdx.x;
  const float* xt = x + (size_t)t * H_DIM;
  float acc[E_NUM];
  #pragma unroll
  for (int e = 0; e < E_NUM; e++) acc[e] = 0.f;
  for (int k = l; k < H_DIM; k += 64) {
    float xv = xt[k];
    #pragma unroll
    for (int e = 0; e < E_NUM; e++) acc[e] += xv * gw[e * H_DIM + k];
  }
  // shared-expert row write (all 64 lanes; x re-read hits L1/L2)
  unsigned short* xrow = xg + (size_t)(2 * T_TOK + t) * H_DIM;
  #pragma unroll
  for (int i = 0; i < 4; i++) {
    int idx = l + i * 64;                  // float4 index 0..255
    float4 v = *(const float4*)(xt + idx * 4);
    ushort4 o;
    o.x = f2bf(v.x); o.y = f2bf(v.y); o.z = f2bf(v.z); o.w = f2bf(v.w);
    *(ushort4*)(xrow + idx * 4) = o;
  }
  #pragma unroll
  for (int e = 0; e < E_NUM; e++) {
    float v = acc[e];
    #pragma unroll
    for (int off = 32; off > 0; off >>= 1) v += __shfl_xor(v, off, 64);
    acc[e] = v;
  }
  if (l == 0) {
    float s[E_NUM];
    #pragma unroll
    for (int e = 0; e < E_NUM; e++) s[e] = 1.f / (1.f + __expf(-(acc[e] + gb[e])));
    int i1 = 0; float v1 = s[0];
    #pragma unroll
    for (int e = 1; e < E_NUM; e++) if (s[e] > v1) { v1 = s[e]; i1 = e; }
    int i2 = -1; float v2 = -1.f;
    #pragma unroll
    for (int e = 0; e < E_NUM; e++) if (e != i1 && s[e] > v2) { v2 = s[e]; i2 = e; }
    float denom = v1 + v2 + 1e-6f;
    topidx[t * 2]     = i1; topidx[t * 2 + 1] = i2;
    topw[t * 2]       = v1 / denom;
    topw[t * 2 + 1]   = v2 / denom;
    atomicAdd(&counts[i1], 1);
    atomicAdd(&counts[i2], 1);
  }
}

// prefix offsets over {8 routed experts} + shared(e=8, cnt=T_TOK)
__global__ void scan_kernel(const int* __restrict__ counts, int* __restrict__ offs,
                            int* __restrict__ cursor) {
  if (threadIdx.x == 0) {
    int a = 0;
    for (int e = 0; e < E_NUM; e++) { offs[e] = a; a += counts[e]; cursor[e] = 0; }
    offs[E_NUM] = a;                 // == 8192
    offs[E_NUM + 1] = a + T_TOK;     // shared slots 8192..12287
  }
}

__global__ void dispatch_kernel(const int* __restrict__ topidx,
                                const int* __restrict__ offs, int* __restrict__ cursor,
                                int* __restrict__ gidx, int* __restrict__ slot_of) {
  int t = blockIdx.x * blockDim.x + threadIdx.x;
  if (t >= T_TOK) return;
  #pragma unroll
  for (int j = 0; j < 2; j++) {
    int ex  = topidx[t * 2 + j];
    int pos = atomicAdd(&cursor[ex], 1);
    int slot = offs[ex] + pos;
    gidx[slot] = t;
    slot_of[t * 2 + j] = slot;
  }
}

// FUSED: w1 transpose-cast (9216 blocks, independent long pole, runs first) +
// routed-token gather-cast (8192 blocks; shared rows are written by gate).
#define W1T_BLOCKS (64 * 16 * (E_NUM + 1))   // (FF/64) x (H/64) x 9 = 9216
__global__ __launch_bounds__(256) void gather_w1t_kernel(
    const float* __restrict__ x, const int* __restrict__ gidx,
    unsigned short* __restrict__ xg,
    const float* __restrict__ w1, const float* __restrict__ sw1,
    unsigned short* __restrict__ w1t) {
  __shared__ float tile[64][65];
  const int bid = blockIdx.x;

  if (bid < W1T_BLOCKS) {
    // ---- w1 transpose: in [z][R=H][C=FF] f32 -> out [z][C][R] bf16 ----
    const int z   = bid >> 10;          // 0..8
    const int rem = bid & 1023;
    const int c0 = (rem & 63) * 64;     // C (FF) tile
    const int r0 = (rem >> 6) * 64;     // R (H) tile
    const float* inb = (z < E_NUM) ? (w1 + (size_t)z * H_DIM * FF_DIM) : sw1;
    unsigned short* outb = w1t + (size_t)z * H_DIM * FF_DIM;
    const int tx = threadIdx.x & 15, ty = threadIdx.x >> 4;   // 16 x 16
    #pragma unroll
    for (int i = 0; i < 4; i++) {
      int row = ty + i * 16;
      float4 v = *(const float4*)(inb + (size_t)(r0 + row) * FF_DIM + c0 + tx * 4);
      tile[row][tx * 4 + 0] = v.x;
      tile[row][tx * 4 + 1] = v.y;
      tile[row][tx * 4 + 2] = v.z;
      tile[row][tx * 4 + 3] = v.w;
    }
    __syncthreads();
    int rr0 = tx * 4;
    #pragma unroll
    for (int p = 0; p < 4; p++) {
      int col = p * 16 + ty;
      ushort4 o;
      o.x = f2bf(tile[rr0 + 0][col]);
      o.y = f2bf(tile[rr0 + 1][col]);
      o.z = f2bf(tile[rr0 + 2][col]);
      o.w = f2bf(tile[rr0 + 3][col]);
      *(ushort4*)(outb + (size_t)(c0 + col) * H_DIM + r0 + rr0) = o;
    }
    return;
  }

  // ---- routed gather + cast: xg[slot][:] = bf16(x[gidx[slot]][:]) ----
  const int slot = bid - W1T_BLOCKS;     // 0..8191
  const int g = threadIdx.x;             // 256 threads x float4 = 1024 elems
  int tok = gidx[slot];
  float4 v = *(const float4*)(x + (size_t)tok * H_DIM + g * 4);
  ushort4 o;
  o.x = f2bf(v.x); o.y = f2bf(v.y); o.z = f2bf(v.z); o.w = f2bf(v.w);
  *(ushort4*)(xg + (size_t)slot * H_DIM + g * 4) = o;
}

// ---------------- GEMM 64x256, BK=64, 4 waves (1Mx4N), m97 single-buffer ----
// FINAL config (best measured: 525us total, ~180us/GEMM). Why frozen:
// - 4x4 f32x4 acc (64 AGPR) + 64 VGPR = 128 unified regs/wave -> 16 waves/CU
//   register ceiling (m69) -> 4 blocks/CU is the HW-maximal co-residency for
//   this accumulator; measured alternatives all regress: dbuf@2blk (r11: 202us),
//   8-phase@1blk (r2: 294us), BM=128 (r10: 206us), grid swap (r13: 235us).
// - grid x=n-panel (fastest), y=m-tile, z=expert: consecutive ids share the A
//   tile; FETCH 296MB vs 450-460MB for other orderings.
// - launch_bounds (256,4): VGPR cap 128, no spill (r9: (512,6) spilled acc).
// - FFN1 z=9 slice transposes w2 -> wAll2 riding FFN1's idle memory pipe.
// Per-wave output 64x64 (acc 4x4); all 4 waves share the A fragments.
// LDS rows of 64 bf16 (128B = 8x16B units), XOR swizzle u' = u ^ (row&7),
// staged via global_load_lds (linear dest, pre-swizzled global source).
// B columns permuted within each 64-group: LDS row r (rr=r&63) holds weight col
// n0 + (r&192) + 4*(rr&15) + (rr>>4) -> lane owns 4 adjacent cols -> coalesced stores.
template <bool FFN1>
__global__ __launch_bounds__(256, 4) void gemm64x256(
    const unsigned short* __restrict__ A,    // FFN1: xg [12288][1024]; else hdn [12288][4096]
    const unsigned short* __restrict__ Bt,   // wAll [9][N][K] (K-contig)
    const float* __restrict__ b_r,           // routed bias [8][N]
    const float* __restrict__ b_s,           // shared bias [N]
    unsigned short* __restrict__ outp,       // FFN1: hdn bf16; else y bf16
    const int* __restrict__ offs,            // [10]
    const float* __restrict__ w2src,         // FFN1 fusion: w2 [8][FF][H] f32
    const float* __restrict__ sw2src,        // FFN1 fusion: sw2 [FF][H] f32
    unsigned short* __restrict__ w2t,        // FFN1 fusion: wAll2 [9][H][FF] bf16
    int K, int N) {
  __shared__ __align__(16) char ldsA[64 * 128];    //  8 KB
  __shared__ __align__(16) char ldsB[256 * 128];   // 32 KB

  // ---- fused w2 transpose slice (FFN1 only, z == 9) ----
  // x in [0,16): H/64 col-tiles; y in [0,64): FF/64 row-tiles
  if (FFN1 && blockIdx.z == E_NUM + 1) {
    float (*tile)[65] = (float (*)[65])ldsB;       // 16.6 KB, fits in ldsB
    const int c0 = blockIdx.x * 64;                // H cols
    const int r0 = blockIdx.y * 64;                // FF rows
    const int tx = threadIdx.x & 15, ty = threadIdx.x >> 4;
    for (int z2 = 0; z2 <= E_NUM; z2++) {
      const float* inb = (z2 < E_NUM) ? (w2src + (size_t)z2 * FF_DIM * H_DIM) : sw2src;
      unsigned short* outb = w2t + (size_t)z2 * FF_DIM * H_DIM;
      #pragma unroll
      for (int i = 0; i < 4; i++) {
        int row = ty + i * 16;
        float4 v = *(const float4*)(inb + (size_t)(r0 + row) * H_DIM + c0 + tx * 4);
        tile[row][tx * 4 + 0] = v.x;
        tile[row][tx * 4 + 1] = v.y;
        tile[row][tx * 4 + 2] = v.z;
        tile[row][tx * 4 + 3] = v.w;
      }
      __syncthreads();
      int rr0 = tx * 4;
      #pragma unroll
      for (int p = 0; p < 4; p++) {
        int col = p * 16 + ty;
        ushort4 o;
        o.x = f2bf(tile[rr0 + 0][col]);
        o.y = f2bf(tile[rr0 + 1][col]);
        o.z = f2bf(tile[rr0 + 2][col]);
        o.w = f2bf(tile[rr0 + 3][col]);
        *(ushort4*)(outb + (size_t)(c0 + col) * FF_DIM + r0 + rr0) = o;
      }
      __syncthreads();   // tile reused by next expert
    }
    return;
  }

  // ---- GEMM path (z in [0, 9)) ----
  const int e  = blockIdx.z;
  const int m0 = blockIdx.y * 64;
  const int cnt = offs[e + 1] - offs[e];
  if (m0 >= cnt) return;
  const int base  = offs[e] + m0;
  const int valid = min(64, cnt - m0);
  const int n0 = blockIdx.x * 256;

  const int tid = threadIdx.x;
  const int l = tid & 63;

  // staging: per K-tile, A = 2 chunks/thread, B = 8 chunks/thread (16B each)
  const int srow = tid >> 3;               // 0..31 (+32j)
  const int su   = (tid & 7) ^ (srow & 7); // pre-swizzled source 16B-unit
  const unsigned short* aSrc[2];
  const unsigned short* bSrc[8];
  const unsigned short* BtE = Bt + (size_t)e * (size_t)N * (size_t)K;
  #pragma unroll
  for (int j = 0; j < 2; j++)
    aSrc[j] = A + (size_t)(base + j * 32 + srow) * (size_t)K + su * 8;
  #pragma unroll
  for (int j = 0; j < 8; j++) {
    int r = j * 32 + srow;                 // B tile row 0..255
    int rr = r & 63;
    int nr = n0 + (r & 192) + ((rr & 15) << 2) + (rr >> 4);   // col permutation
    bSrc[j] = BtE + (size_t)nr * (size_t)K + su * 8;
  }

  f32x4 acc[4][4];
  #pragma unroll
  for (int m = 0; m < 4; m++)
    #pragma unroll
    for (int n = 0; n < 4; n++) acc[m][n] = (f32x4){0.f, 0.f, 0.f, 0.f};

  const int wc = tid >> 6;                // wave 0..3 = N-group
  const int l15 = l & 15, l4 = l >> 4, l7 = l & 7;

  for (int kt = 0; kt < K; kt += 64) {
    #pragma unroll
    for (int j = 0; j < 2; j++)
      __builtin_amdgcn_global_load_lds((const AS1 void*)(aSrc[j] + kt),
                                       (AS3 void*)(ldsA + (j * 256 + tid) * 16), 16, 0, 0);
    #pragma unroll
    for (int j = 0; j < 8; j++)
      __builtin_amdgcn_global_load_lds((const AS1 void*)(bSrc[j] + kt),
                                       (AS3 void*)(ldsB + (j * 256 + tid) * 16), 16, 0, 0);
    __syncthreads();   // drains vmcnt before barrier
    #pragma unroll
    for (int kk = 0; kk < 2; kk++) {
      const int uoff = ((kk * 4 + l4) ^ l7) << 4;
      bf16x8 af[4], bfr[4];
      #pragma unroll
      for (int m = 0; m < 4; m++)
        af[m] = *(const bf16x8*)(ldsA + (m * 16 + l15) * 128 + uoff);
      #pragma unroll
      for (int n = 0; n < 4; n++)
        bfr[n] = *(const bf16x8*)(ldsB + (wc * 64 + n * 16 + l15) * 128 + uoff);
      #pragma unroll
      for (int m = 0; m < 4; m++)
        #pragma unroll
        for (int n = 0; n < 4; n++)
          acc[m][n] = __builtin_amdgcn_mfma_f32_16x16x32_bf16(af[m], bfr[n], acc[m][n], 0, 0, 0);
    }
    __syncthreads();
  }

  // epilogue: lane owns cols c0..c0+3 (B-permutation); C/D row = l4*4+j
  const float* bias = (e < E_NUM) ? (b_r + (size_t)e * N) : b_s;
  const int c0 = n0 + wc * 64 + 4 * l15;
  float4 bv = *(const float4*)(bias + c0);
  #pragma unroll
  for (int m = 0; m < 4; m++) {
    #pragma unroll
    for (int j = 0; j < 4; j++) {
      int rl = m * 16 + l4 * 4 + j;
      if (rl < valid) {
        ushort4 o;
        if (FFN1) {
          o.x = f2bf(gelu_f(acc[m][0][j] + bv.x));
          o.y = f2bf(gelu_f(acc[m][1][j] + bv.y));
          o.z = f2bf(gelu_f(acc[m][2][j] + bv.z));
          o.w = f2bf(gelu_f(acc[m][3][j] + bv.w));
        } else {
          o.x = f2bf(acc[m][0][j] + bv.x);
          o.y = f2bf(acc[m][1][j] + bv.y);
          o.z = f2bf(acc[m][2][j] + bv.z);
          o.w = f2bf(acc[m][3][j] + bv.w);
        }
        *(ushort4*)(outp + (size_t)(base + rl) * N + c0) = o;
      }
    }
  }
}

// out[t] = w1*y[s1] + w2*y[s2] + 0.1*y[8192+t]   (biases already in y; y bf16)
__global__ __launch_bounds__(256) void combine_kernel(
    const unsigned short* __restrict__ y, const float* __restrict__ topw,
    const int* __restrict__ slot_of, float* __restrict__ out) {
  int t = blockIdx.x;
  int g = threadIdx.x;
  int s1 = slot_of[2 * t], s2 = slot_of[2 * t + 1];
  float w1 = topw[2 * t], w2 = topw[2 * t + 1];
  ushort4 a = *(const ushort4*)(y + (size_t)s1 * H_DIM + g * 4);
  ushort4 b = *(const ushort4*)(y + (size_t)s2 * H_DIM + g * 4);
  ushort4 c = *(const ushort4*)(y + (size_t)(2 * T_TOK + t) * H_DIM + g * 4);
  float4 o;
  o.x = w1 * bf2f(a.x) + w2 * bf2f(b.x) + 0.1f * bf2f(c.x);
  o.y = w1 * bf2f(a.y) + w2 * bf2f(b.y) + 0.1f * bf2f(c.y);
  o.z = w1 * bf2f(a.z) + w2 * bf2f(b.z) + 0.1f * bf2f(c.z);
  o.w = w1 * bf2f(a.w) + w2 * bf2f(b.w) + 0.1f * bf2f(c.w);
  *(float4*)(out + (size_t)t * H_DIM + g * 4) = o;
}

// ---------------- host ----------------
extern "C" void kernel_launch(void* const* d_in, const int* in_sizes, int n_in,
                              void* d_out, int out_size, void* d_ws, size_t ws_size,
                              hipStream_t stream) {
  const float* x   = (const float*)d_in[0];
  const float* gw  = (const float*)d_in[1];
  const float* gb  = (const float*)d_in[2];
  const float* w1  = (const float*)d_in[3];
  const float* b1  = (const float*)d_in[4];
  const float* w2  = (const float*)d_in[5];
  const float* b2  = (const float*)d_in[6];
  const float* sw1 = (const float*)d_in[7];
  const float* sb1 = (const float*)d_in[8];
  const float* sw2 = (const float*)d_in[9];
  const float* sb2 = (const float*)d_in[10];
  float* out = (float*)d_out;

  char* p = (char*)d_ws;
  auto alloc = [&](size_t bytes) {
    char* r = p;
    p += (bytes + 255) & ~(size_t)255;
    return r;
  };
  int*   counts  = (int*)alloc(E_NUM * 4);
  int*   cursor  = (int*)alloc(E_NUM * 4);
  int*   offs    = (int*)alloc((E_NUM + 2) * 4);
  int*   topidx  = (int*)alloc((size_t)T_TOK * 2 * 4);
  float* topw    = (float*)alloc((size_t)T_TOK * 2 * 4);
  int*   slot_of = (int*)alloc((size_t)T_TOK * 2 * 4);
  int*   gidx    = (int*)alloc((size_t)2 * T_TOK * 4);
  unsigned short* xg    = (unsigned short*)alloc((size_t)3 * T_TOK * H_DIM * 2);   // 24 MB
  unsigned short* wAll1 = (unsigned short*)alloc((size_t)(E_NUM + 1) * FF_DIM * H_DIM * 2);  // 72 MB
  unsigned short* wAll2 = (unsigned short*)alloc((size_t)(E_NUM + 1) * FF_DIM * H_DIM * 2);  // 72 MB
  unsigned short* hdn   = (unsigned short*)alloc((size_t)3 * T_TOK * FF_DIM * 2);  // 96 MB
  unsigned short* yb    = (unsigned short*)alloc((size_t)3 * T_TOK * H_DIM * 2);   // 24 MB

  // routing (counts zeroed via memset node; gate also emits shared-expert rows)
  hipMemsetAsync(counts, 0, E_NUM * 4, stream);
  gate_kernel<<<T_TOK, 64, 0, stream>>>(x, gw, gb, topidx, topw, counts, xg);
  scan_kernel<<<1, 1, 0, stream>>>(counts, offs, cursor);
  dispatch_kernel<<<T_TOK / 256, 256, 0, stream>>>(topidx, offs, cursor, gidx, slot_of);

  // FUSED: w1 transpose-cast (independent) + routed-token gather-cast
  gather_w1t_kernel<<<W1T_BLOCKS + 2 * T_TOK, 256, 0, stream>>>(
      x, gidx, xg, w1, sw1, wAll1);

  // FFN1 GEMM (grid: x=n-panels, y=m-tiles) + fused w2 transpose (z=9)
  gemm64x256<true><<<dim3(FF_DIM / 256, T_TOK / 64, E_NUM + 2), 256, 0, stream>>>(
      xg, wAll1, b1, sb1, hdn, offs, w2, sw2, wAll2, H_DIM, FF_DIM);

  // FFN2 GEMM (grid: x=n-panels, y=m-tiles)
  gemm64x256<false><<<dim3(H_DIM / 256, T_TOK / 64, E_NUM + 1), 256, 0, stream>>>(
      hdn, wAll2, b2, sb2, yb, offs, nullptr, nullptr, nullptr, FF_DIM, H_DIM);

  // weighted combine (routed top-2 + 0.1 * shared)
  combine_kernel<<<T_TOK, 256, 0, stream>>>(yb, topw, slot_of, out);
}

// Round 19
// 505.086 us; speedup vs baseline: 1.0428x; 1.0428x over previous
//
#include <hip/hip_runtime.h>
#include <stdint.h>

#define H_DIM 1024
#define E_NUM 8
#define FF_DIM 4096
#define T_TOK 4096   // B*S = 2*2048

typedef __bf16 bf16x8 __attribute__((ext_vector_type(8)));
typedef float f32x4 __attribute__((ext_vector_type(4)));

#define AS1 __attribute__((address_space(1)))
#define AS3 __attribute__((address_space(3)))

__device__ __forceinline__ unsigned short f2bf(float f) {
  union { float f; uint32_t u; } v; v.f = f;
  uint32_t u = v.u;
  uint32_t r = u + 0x7fffu + ((u >> 16) & 1u);   // RNE
  return (unsigned short)(r >> 16);
}
__device__ __forceinline__ float bf2f(unsigned short u) {
  union { uint32_t u; float f; } v; v.u = ((uint32_t)u) << 16;
  return v.f;
}

// tanh-form GELU: max |err| vs exact-erf gelu ~1e-3 (budget: 5e-2 abs)
__device__ __forceinline__ float gelu_f(float x) {
  float s = x * x;
  float g = x * (1.5957691216f + 0.0713548162f * s);
  float t = __expf(-g);
  return x * __builtin_amdgcn_rcpf(1.0f + t);
}

// ---------------- FUSED gate + w1 transpose (both dependency-free, r18 move:
// w1t no longer waits behind the gate->scan->dispatch serial chain) ----------
// bid < T_TOK/4: gating, 4 tokens/block (one wave each); also writes the
//   shared-expert bf16 row (slot 8192+t needs no dispatch info).
// bid >= T_TOK/4: w1 transpose-cast [z][H][FF] f32 -> [z][FF][H] bf16.
#define GATE_BLOCKS (T_TOK / 4)              // 1024
#define W1T_BLOCKS (64 * 16 * (E_NUM + 1))   // (FF/64) x (H/64) x 9 = 9216
__global__ __launch_bounds__(256) void gate_w1t_kernel(
    const float* __restrict__ x, const float* __restrict__ gw, const float* __restrict__ gb,
    int* __restrict__ topidx, float* __restrict__ topw, int* __restrict__ counts,
    unsigned short* __restrict__ xg,
    const float* __restrict__ w1, const float* __restrict__ sw1,
    unsigned short* __restrict__ w1t) {
  __shared__ float tile[64][65];
  const int bid = blockIdx.x;

  if (bid < GATE_BLOCKS) {
    // ---- gating: one wave per token ----
    const int t = bid * 4 + (threadIdx.x >> 6);
    const int l = threadIdx.x & 63;
    const float* xt = x + (size_t)t * H_DIM;
    float acc[E_NUM];
    #pragma unroll
    for (int e = 0; e < E_NUM; e++) acc[e] = 0.f;
    for (int k = l; k < H_DIM; k += 64) {
      float xv = xt[k];
      #pragma unroll
      for (int e = 0; e < E_NUM; e++) acc[e] += xv * gw[e * H_DIM + k];
    }
    // shared-expert row write (all 64 lanes; x re-read hits L1/L2)
    unsigned short* xrow = xg + (size_t)(2 * T_TOK + t) * H_DIM;
    #pragma unroll
    for (int i = 0; i < 4; i++) {
      int idx = l + i * 64;                  // float4 index 0..255
      float4 v = *(const float4*)(xt + idx * 4);
      ushort4 o;
      o.x = f2bf(v.x); o.y = f2bf(v.y); o.z = f2bf(v.z); o.w = f2bf(v.w);
      *(ushort4*)(xrow + idx * 4) = o;
    }
    #pragma unroll
    for (int e = 0; e < E_NUM; e++) {
      float v = acc[e];
      #pragma unroll
      for (int off = 32; off > 0; off >>= 1) v += __shfl_xor(v, off, 64);
      acc[e] = v;
    }
    if (l == 0) {
      float s[E_NUM];
      #pragma unroll
      for (int e = 0; e < E_NUM; e++) s[e] = 1.f / (1.f + __expf(-(acc[e] + gb[e])));
      int i1 = 0; float v1 = s[0];
      #pragma unroll
      for (int e = 1; e < E_NUM; e++) if (s[e] > v1) { v1 = s[e]; i1 = e; }
      int i2 = -1; float v2 = -1.f;
      #pragma unroll
      for (int e = 0; e < E_NUM; e++) if (e != i1 && s[e] > v2) { v2 = s[e]; i2 = e; }
      float denom = v1 + v2 + 1e-6f;
      topidx[t * 2]     = i1; topidx[t * 2 + 1] = i2;
      topw[t * 2]       = v1 / denom;
      topw[t * 2 + 1]   = v2 / denom;
      atomicAdd(&counts[i1], 1);
      atomicAdd(&counts[i2], 1);
    }
    return;
  }

  // ---- w1 transpose: in [z][R=H][C=FF] f32 -> out [z][C][R] bf16 ----
  const int tb  = bid - GATE_BLOCKS;    // 0..9215
  const int z   = tb >> 10;             // 0..8
  const int rem = tb & 1023;
  const int c0 = (rem & 63) * 64;       // C (FF) tile
  const int r0 = (rem >> 6) * 64;       // R (H) tile
  const float* inb = (z < E_NUM) ? (w1 + (size_t)z * H_DIM * FF_DIM) : sw1;
  unsigned short* outb = w1t + (size_t)z * H_DIM * FF_DIM;
  const int tx = threadIdx.x & 15, ty = threadIdx.x >> 4;   // 16 x 16
  #pragma unroll
  for (int i = 0; i < 4; i++) {
    int row = ty + i * 16;
    float4 v = *(const float4*)(inb + (size_t)(r0 + row) * FF_DIM + c0 + tx * 4);
    tile[row][tx * 4 + 0] = v.x;
    tile[row][tx * 4 + 1] = v.y;
    tile[row][tx * 4 + 2] = v.z;
    tile[row][tx * 4 + 3] = v.w;
  }
  __syncthreads();
  int rr0 = tx * 4;
  #pragma unroll
  for (int p = 0; p < 4; p++) {
    int col = p * 16 + ty;
    ushort4 o;
    o.x = f2bf(tile[rr0 + 0][col]);
    o.y = f2bf(tile[rr0 + 1][col]);
    o.z = f2bf(tile[rr0 + 2][col]);
    o.w = f2bf(tile[rr0 + 3][col]);
    *(ushort4*)(outb + (size_t)(c0 + col) * H_DIM + r0 + rr0) = o;
  }
}

// prefix offsets over {8 routed experts} + shared(e=8, cnt=T_TOK)
__global__ void scan_kernel(const int* __restrict__ counts, int* __restrict__ offs,
                            int* __restrict__ cursor) {
  if (threadIdx.x == 0) {
    int a = 0;
    for (int e = 0; e < E_NUM; e++) { offs[e] = a; a += counts[e]; cursor[e] = 0; }
    offs[E_NUM] = a;                 // == 8192
    offs[E_NUM + 1] = a + T_TOK;     // shared slots 8192..12287
  }
}

__global__ void dispatch_kernel(const int* __restrict__ topidx,
                                const int* __restrict__ offs, int* __restrict__ cursor,
                                int* __restrict__ gidx, int* __restrict__ slot_of) {
  int t = blockIdx.x * blockDim.x + threadIdx.x;
  if (t >= T_TOK) return;
  #pragma unroll
  for (int j = 0; j < 2; j++) {
    int ex  = topidx[t * 2 + j];
    int pos = atomicAdd(&cursor[ex], 1);
    int slot = offs[ex] + pos;
    gidx[slot] = t;
    slot_of[t * 2 + j] = slot;
  }
}

// routed gather + cast: xg[slot][:] = bf16(x[gidx[slot]][:]) (slots 0..8191;
// shared rows were written by gate)
__global__ __launch_bounds__(256) void gather_x_kernel(
    const float* __restrict__ x, const int* __restrict__ gidx,
    unsigned short* __restrict__ xg) {
  int slot = blockIdx.x;
  int g = threadIdx.x;                     // 256 threads x float4 = 1024 elems
  int tok = gidx[slot];
  float4 v = *(const float4*)(x + (size_t)tok * H_DIM + g * 4);
  ushort4 o;
  o.x = f2bf(v.x); o.y = f2bf(v.y); o.z = f2bf(v.z); o.w = f2bf(v.w);
  *(ushort4*)(xg + (size_t)slot * H_DIM + g * 4) = o;
}

// ---------------- GEMM 64x256, BK=64, 4 waves (1Mx4N), m97 single-buffer ----
// FINAL config (best measured: 525us total, ~180us/GEMM). Why frozen:
// - 4x4 f32x4 acc (64 AGPR) + 64 VGPR = 128 unified regs/wave -> 16 waves/CU
//   register ceiling (m69) -> 4 blocks/CU is the HW-maximal co-residency for
//   this accumulator; measured alternatives all regress: dbuf@2blk (r11: 202us),
//   8-phase@1blk (r2: 294us), BM=128 (r10: 206us), grid swap (r13: 235us).
// - grid x=n-panel (fastest), y=m-tile, z=expert: consecutive ids share the A
//   tile; FETCH 296MB vs 450-460MB for other orderings.
// - launch_bounds (256,4): VGPR cap 128, no spill (r9: (512,6) spilled acc).
// - FFN1 z=9 slice transposes w2 -> wAll2 riding FFN1's idle memory pipe.
// Per-wave output 64x64 (acc 4x4); all 4 waves share the A fragments.
// LDS rows of 64 bf16 (128B = 8x16B units), XOR swizzle u' = u ^ (row&7),
// staged via global_load_lds (linear dest, pre-swizzled global source).
// B columns permuted within each 64-group: LDS row r (rr=r&63) holds weight col
// n0 + (r&192) + 4*(rr&15) + (rr>>4) -> lane owns 4 adjacent cols -> coalesced stores.
template <bool FFN1>
__global__ __launch_bounds__(256, 4) void gemm64x256(
    const unsigned short* __restrict__ A,    // FFN1: xg [12288][1024]; else hdn [12288][4096]
    const unsigned short* __restrict__ Bt,   // wAll [9][N][K] (K-contig)
    const float* __restrict__ b_r,           // routed bias [8][N]
    const float* __restrict__ b_s,           // shared bias [N]
    unsigned short* __restrict__ outp,       // FFN1: hdn bf16; else y bf16
    const int* __restrict__ offs,            // [10]
    const float* __restrict__ w2src,         // FFN1 fusion: w2 [8][FF][H] f32
    const float* __restrict__ sw2src,        // FFN1 fusion: sw2 [FF][H] f32
    unsigned short* __restrict__ w2t,        // FFN1 fusion: wAll2 [9][H][FF] bf16
    int K, int N) {
  __shared__ __align__(16) char ldsA[64 * 128];    //  8 KB
  __shared__ __align__(16) char ldsB[256 * 128];   // 32 KB

  // ---- fused w2 transpose slice (FFN1 only, z == 9) ----
  // x in [0,16): H/64 col-tiles; y in [0,64): FF/64 row-tiles
  if (FFN1 && blockIdx.z == E_NUM + 1) {
    float (*tile)[65] = (float (*)[65])ldsB;       // 16.6 KB, fits in ldsB
    const int c0 = blockIdx.x * 64;                // H cols
    const int r0 = blockIdx.y * 64;                // FF rows
    const int tx = threadIdx.x & 15, ty = threadIdx.x >> 4;
    for (int z2 = 0; z2 <= E_NUM; z2++) {
      const float* inb = (z2 < E_NUM) ? (w2src + (size_t)z2 * FF_DIM * H_DIM) : sw2src;
      unsigned short* outb = w2t + (size_t)z2 * FF_DIM * H_DIM;
      #pragma unroll
      for (int i = 0; i < 4; i++) {
        int row = ty + i * 16;
        float4 v = *(const float4*)(inb + (size_t)(r0 + row) * H_DIM + c0 + tx * 4);
        tile[row][tx * 4 + 0] = v.x;
        tile[row][tx * 4 + 1] = v.y;
        tile[row][tx * 4 + 2] = v.z;
        tile[row][tx * 4 + 3] = v.w;
      }
      __syncthreads();
      int rr0 = tx * 4;
      #pragma unroll
      for (int p = 0; p < 4; p++) {
        int col = p * 16 + ty;
        ushort4 o;
        o.x = f2bf(tile[rr0 + 0][col]);
        o.y = f2bf(tile[rr0 + 1][col]);
        o.z = f2bf(tile[rr0 + 2][col]);
        o.w = f2bf(tile[rr0 + 3][col]);
        *(ushort4*)(outb + (size_t)(c0 + col) * FF_DIM + r0 + rr0) = o;
      }
      __syncthreads();   // tile reused by next expert
    }
    return;
  }

  // ---- GEMM path (z in [0, 9)) ----
  const int e  = blockIdx.z;
  const int m0 = blockIdx.y * 64;
  const int cnt = offs[e + 1] - offs[e];
  if (m0 >= cnt) return;
  const int base  = offs[e] + m0;
  const int valid = min(64, cnt - m0);
  const int n0 = blockIdx.x * 256;

  const int tid = threadIdx.x;
  const int l = tid & 63;

  // staging: per K-tile, A = 2 chunks/thread, B = 8 chunks/thread (16B each)
  const int srow = tid >> 3;               // 0..31 (+32j)
  const int su   = (tid & 7) ^ (srow & 7); // pre-swizzled source 16B-unit
  const unsigned short* aSrc[2];
  const unsigned short* bSrc[8];
  const unsigned short* BtE = Bt + (size_t)e * (size_t)N * (size_t)K;
  #pragma unroll
  for (int j = 0; j < 2; j++)
    aSrc[j] = A + (size_t)(base + j * 32 + srow) * (size_t)K + su * 8;
  #pragma unroll
  for (int j = 0; j < 8; j++) {
    int r = j * 32 + srow;                 // B tile row 0..255
    int rr = r & 63;
    int nr = n0 + (r & 192) + ((rr & 15) << 2) + (rr >> 4);   // col permutation
    bSrc[j] = BtE + (size_t)nr * (size_t)K + su * 8;
  }

  f32x4 acc[4][4];
  #pragma unroll
  for (int m = 0; m < 4; m++)
    #pragma unroll
    for (int n = 0; n < 4; n++) acc[m][n] = (f32x4){0.f, 0.f, 0.f, 0.f};

  const int wc = tid >> 6;                // wave 0..3 = N-group
  const int l15 = l & 15, l4 = l >> 4, l7 = l & 7;

  for (int kt = 0; kt < K; kt += 64) {
    #pragma unroll
    for (int j = 0; j < 2; j++)
      __builtin_amdgcn_global_load_lds((const AS1 void*)(aSrc[j] + kt),
                                       (AS3 void*)(ldsA + (j * 256 + tid) * 16), 16, 0, 0);
    #pragma unroll
    for (int j = 0; j < 8; j++)
      __builtin_amdgcn_global_load_lds((const AS1 void*)(bSrc[j] + kt),
                                       (AS3 void*)(ldsB + (j * 256 + tid) * 16), 16, 0, 0);
    __syncthreads();   // drains vmcnt before barrier
    #pragma unroll
    for (int kk = 0; kk < 2; kk++) {
      const int uoff = ((kk * 4 + l4) ^ l7) << 4;
      bf16x8 af[4], bfr[4];
      #pragma unroll
      for (int m = 0; m < 4; m++)
        af[m] = *(const bf16x8*)(ldsA + (m * 16 + l15) * 128 + uoff);
      #pragma unroll
      for (int n = 0; n < 4; n++)
        bfr[n] = *(const bf16x8*)(ldsB + (wc * 64 + n * 16 + l15) * 128 + uoff);
      #pragma unroll
      for (int m = 0; m < 4; m++)
        #pragma unroll
        for (int n = 0; n < 4; n++)
          acc[m][n] = __builtin_amdgcn_mfma_f32_16x16x32_bf16(af[m], bfr[n], acc[m][n], 0, 0, 0);
    }
    __syncthreads();
  }

  // epilogue: lane owns cols c0..c0+3 (B-permutation); C/D row = l4*4+j
  const float* bias = (e < E_NUM) ? (b_r + (size_t)e * N) : b_s;
  const int c0 = n0 + wc * 64 + 4 * l15;
  float4 bv = *(const float4*)(bias + c0);
  #pragma unroll
  for (int m = 0; m < 4; m++) {
    #pragma unroll
    for (int j = 0; j < 4; j++) {
      int rl = m * 16 + l4 * 4 + j;
      if (rl < valid) {
        ushort4 o;
        if (FFN1) {
          o.x = f2bf(gelu_f(acc[m][0][j] + bv.x));
          o.y = f2bf(gelu_f(acc[m][1][j] + bv.y));
          o.z = f2bf(gelu_f(acc[m][2][j] + bv.z));
          o.w = f2bf(gelu_f(acc[m][3][j] + bv.w));
        } else {
          o.x = f2bf(acc[m][0][j] + bv.x);
          o.y = f2bf(acc[m][1][j] + bv.y);
          o.z = f2bf(acc[m][2][j] + bv.z);
          o.w = f2bf(acc[m][3][j] + bv.w);
        }
        *(ushort4*)(outp + (size_t)(base + rl) * N + c0) = o;
      }
    }
  }
}

// out[t] = w1*y[s1] + w2*y[s2] + 0.1*y[8192+t]   (biases already in y; y bf16)
__global__ __launch_bounds__(256) void combine_kernel(
    const unsigned short* __restrict__ y, const float* __restrict__ topw,
    const int* __restrict__ slot_of, float* __restrict__ out) {
  int t = blockIdx.x;
  int g = threadIdx.x;
  int s1 = slot_of[2 * t], s2 = slot_of[2 * t + 1];
  float w1 = topw[2 * t], w2 = topw[2 * t + 1];
  ushort4 a = *(const ushort4*)(y + (size_t)s1 * H_DIM + g * 4);
  ushort4 b = *(const ushort4*)(y + (size_t)s2 * H_DIM + g * 4);
  ushort4 c = *(const ushort4*)(y + (size_t)(2 * T_TOK + t) * H_DIM + g * 4);
  float4 o;
  o.x = w1 * bf2f(a.x) + w2 * bf2f(b.x) + 0.1f * bf2f(c.x);
  o.y = w1 * bf2f(a.y) + w2 * bf2f(b.y) + 0.1f * bf2f(c.y);
  o.z = w1 * bf2f(a.z) + w2 * bf2f(b.z) + 0.1f * bf2f(c.z);
  o.w = w1 * bf2f(a.w) + w2 * bf2f(b.w) + 0.1f * bf2f(c.w);
  *(float4*)(out + (size_t)t * H_DIM + g * 4) = o;
}

// ---------------- host ----------------
extern "C" void kernel_launch(void* const* d_in, const int* in_sizes, int n_in,
                              void* d_out, int out_size, void* d_ws, size_t ws_size,
                              hipStream_t stream) {
  const float* x   = (const float*)d_in[0];
  const float* gw  = (const float*)d_in[1];
  const float* gb  = (const float*)d_in[2];
  const float* w1  = (const float*)d_in[3];
  const float* b1  = (const float*)d_in[4];
  const float* w2  = (const float*)d_in[5];
  const float* b2  = (const float*)d_in[6];
  const float* sw1 = (const float*)d_in[7];
  const float* sb1 = (const float*)d_in[8];
  const float* sw2 = (const float*)d_in[9];
  const float* sb2 = (const float*)d_in[10];
  float* out = (float*)d_out;

  char* p = (char*)d_ws;
  auto alloc = [&](size_t bytes) {
    char* r = p;
    p += (bytes + 255) & ~(size_t)255;
    return r;
  };
  int*   counts  = (int*)alloc(E_NUM * 4);
  int*   cursor  = (int*)alloc(E_NUM * 4);
  int*   offs    = (int*)alloc((E_NUM + 2) * 4);
  int*   topidx  = (int*)alloc((size_t)T_TOK * 2 * 4);
  float* topw    = (float*)alloc((size_t)T_TOK * 2 * 4);
  int*   slot_of = (int*)alloc((size_t)T_TOK * 2 * 4);
  int*   gidx    = (int*)alloc((size_t)2 * T_TOK * 4);
  unsigned short* xg    = (unsigned short*)alloc((size_t)3 * T_TOK * H_DIM * 2);   // 24 MB
  unsigned short* wAll1 = (unsigned short*)alloc((size_t)(E_NUM + 1) * FF_DIM * H_DIM * 2);  // 72 MB
  unsigned short* wAll2 = (unsigned short*)alloc((size_t)(E_NUM + 1) * FF_DIM * H_DIM * 2);  // 72 MB
  unsigned short* hdn   = (unsigned short*)alloc((size_t)3 * T_TOK * FF_DIM * 2);  // 96 MB
  unsigned short* yb    = (unsigned short*)alloc((size_t)3 * T_TOK * H_DIM * 2);   // 24 MB

  // counts zeroed via memset node
  hipMemsetAsync(counts, 0, E_NUM * 4, stream);

  // FUSED gate + w1 transpose: both dependency-free, so the 9216-block
  // transpose overlaps gating instead of waiting behind gate->scan->dispatch.
  gate_w1t_kernel<<<GATE_BLOCKS + W1T_BLOCKS, 256, 0, stream>>>(
      x, gw, gb, topidx, topw, counts, xg, w1, sw1, wAll1);
  scan_kernel<<<1, 1, 0, stream>>>(counts, offs, cursor);
  dispatch_kernel<<<T_TOK / 256, 256, 0, stream>>>(topidx, offs, cursor, gidx, slot_of);

  // routed-token gather-cast (shared rows already written by gate)
  gather_x_kernel<<<2 * T_TOK, 256, 0, stream>>>(x, gidx, xg);

  // FFN1 GEMM (grid: x=n-panels, y=m-tiles) + fused w2 transpose (z=9)
  gemm64x256<true><<<dim3(FF_DIM / 256, T_TOK / 64, E_NUM + 2), 256, 0, stream>>>(
      xg, wAll1, b1, sb1, hdn, offs, w2, sw2, wAll2, H_DIM, FF_DIM);

  // FFN2 GEMM (grid: x=n-panels, y=m-tiles)
  gemm64x256<false><<<dim3(H_DIM / 256, T_TOK / 64, E_NUM + 1), 256, 0, stream>>>(
      hdn, wAll2, b2, sb2, yb, offs, nullptr, nullptr, nullptr, FF_DIM, H_DIM);

  // weighted combine (routed top-2 + 0.1 * shared)
  combine_kernel<<<T_TOK, 256, 0, stream>>>(yb, topw, slot_of, out);
}

// Round 21
// 494.040 us; speedup vs baseline: 1.0662x; 1.0224x over previous
//
#include <hip/hip_runtime.h>
#include <stdint.h>

#define H_DIM 1024
#define E_NUM 8
#define FF_DIM 4096
#define T_TOK 4096   // B*S = 2*2048

typedef __bf16 bf16x8 __attribute__((ext_vector_type(8)));
typedef float f32x4 __attribute__((ext_vector_type(4)));

#define AS1 __attribute__((address_space(1)))
#define AS3 __attribute__((address_space(3)))

__device__ __forceinline__ unsigned short f2bf(float f) {
  union { float f; uint32_t u; } v; v.f = f;
  uint32_t u = v.u;
  uint32_t r = u + 0x7fffu + ((u >> 16) & 1u);   // RNE
  return (unsigned short)(r >> 16);
}
__device__ __forceinline__ float bf2f(unsigned short u) {
  union { uint32_t u; float f; } v; v.u = ((uint32_t)u) << 16;
  return v.f;
}

// tanh-form GELU: max |err| vs exact-erf gelu ~1e-3 (budget: 5e-2 abs)
__device__ __forceinline__ float gelu_f(float x) {
  float s = x * x;
  float g = x * (1.5957691216f + 0.0713548162f * s);
  float t = __expf(-g);
  return x * __builtin_amdgcn_rcpf(1.0f + t);
}

// ---------------- FUSED gate + w1 transpose (both dependency-free) ----------
// bid < GATE_BLOCKS: gating, 4 tokens/block (one wave each); also writes the
//   token's bf16 row to xb[t] (FFN1 gathers from xb via gidx during staging,
//   so the standalone gather kernel is eliminated).
// bid >= GATE_BLOCKS: w1 transpose-cast [z][H][FF] f32 -> [z][FF][H] bf16.
#define GATE_BLOCKS (T_TOK / 4)              // 1024
#define W1T_BLOCKS (64 * 16 * (E_NUM + 1))   // (FF/64) x (H/64) x 9 = 9216
__global__ __launch_bounds__(256) void gate_w1t_kernel(
    const float* __restrict__ x, const float* __restrict__ gw, const float* __restrict__ gb,
    int* __restrict__ topidx, float* __restrict__ topw, int* __restrict__ counts,
    unsigned short* __restrict__ xb,
    const float* __restrict__ w1, const float* __restrict__ sw1,
    unsigned short* __restrict__ w1t) {
  __shared__ float tile[64][65];
  const int bid = blockIdx.x;

  if (bid < GATE_BLOCKS) {
    // ---- gating: one wave per token ----
    const int t = bid * 4 + (threadIdx.x >> 6);
    const int l = threadIdx.x & 63;
    const float* xt = x + (size_t)t * H_DIM;
    float acc[E_NUM];
    #pragma unroll
    for (int e = 0; e < E_NUM; e++) acc[e] = 0.f;
    for (int k = l; k < H_DIM; k += 64) {
      float xv = xt[k];
      #pragma unroll
      for (int e = 0; e < E_NUM; e++) acc[e] += xv * gw[e * H_DIM + k];
    }
    // token bf16 row write (all 64 lanes; x re-read hits L1/L2)
    unsigned short* xrow = xb + (size_t)t * H_DIM;
    #pragma unroll
    for (int i = 0; i < 4; i++) {
      int idx = l + i * 64;                  // float4 index 0..255
      float4 v = *(const float4*)(xt + idx * 4);
      ushort4 o;
      o.x = f2bf(v.x); o.y = f2bf(v.y); o.z = f2bf(v.z); o.w = f2bf(v.w);
      *(ushort4*)(xrow + idx * 4) = o;
    }
    #pragma unroll
    for (int e = 0; e < E_NUM; e++) {
      float v = acc[e];
      #pragma unroll
      for (int off = 32; off > 0; off >>= 1) v += __shfl_xor(v, off, 64);
      acc[e] = v;
    }
    if (l == 0) {
      float s[E_NUM];
      #pragma unroll
      for (int e = 0; e < E_NUM; e++) s[e] = 1.f / (1.f + __expf(-(acc[e] + gb[e])));
      int i1 = 0; float v1 = s[0];
      #pragma unroll
      for (int e = 1; e < E_NUM; e++) if (s[e] > v1) { v1 = s[e]; i1 = e; }
      int i2 = -1; float v2 = -1.f;
      #pragma unroll
      for (int e = 0; e < E_NUM; e++) if (e != i1 && s[e] > v2) { v2 = s[e]; i2 = e; }
      float denom = v1 + v2 + 1e-6f;
      topidx[t * 2]     = i1; topidx[t * 2 + 1] = i2;
      topw[t * 2]       = v1 / denom;
      topw[t * 2 + 1]   = v2 / denom;
      atomicAdd(&counts[i1], 1);
      atomicAdd(&counts[i2], 1);
    }
    return;
  }

  // ---- w1 transpose: in [z][R=H][C=FF] f32 -> out [z][C][R] bf16 ----
  const int tb  = bid - GATE_BLOCKS;    // 0..9215
  const int z   = tb >> 10;             // 0..8
  const int rem = tb & 1023;
  const int c0 = (rem & 63) * 64;       // C (FF) tile
  const int r0 = (rem >> 6) * 64;       // R (H) tile
  const float* inb = (z < E_NUM) ? (w1 + (size_t)z * H_DIM * FF_DIM) : sw1;
  unsigned short* outb = w1t + (size_t)z * H_DIM * FF_DIM;
  const int tx = threadIdx.x & 15, ty = threadIdx.x >> 4;   // 16 x 16
  #pragma unroll
  for (int i = 0; i < 4; i++) {
    int row = ty + i * 16;
    float4 v = *(const float4*)(inb + (size_t)(r0 + row) * FF_DIM + c0 + tx * 4);
    tile[row][tx * 4 + 0] = v.x;
    tile[row][tx * 4 + 1] = v.y;
    tile[row][tx * 4 + 2] = v.z;
    tile[row][tx * 4 + 3] = v.w;
  }
  __syncthreads();
  int rr0 = tx * 4;
  #pragma unroll
  for (int p = 0; p < 4; p++) {
    int col = p * 16 + ty;
    ushort4 o;
    o.x = f2bf(tile[rr0 + 0][col]);
    o.y = f2bf(tile[rr0 + 1][col]);
    o.z = f2bf(tile[rr0 + 2][col]);
    o.w = f2bf(tile[rr0 + 3][col]);
    *(ushort4*)(outb + (size_t)(c0 + col) * H_DIM + r0 + rr0) = o;
  }
}

// prefix offsets over {8 routed experts} + shared(e=8, cnt=T_TOK)
__global__ void scan_kernel(const int* __restrict__ counts, int* __restrict__ offs,
                            int* __restrict__ cursor) {
  if (threadIdx.x == 0) {
    int a = 0;
    for (int e = 0; e < E_NUM; e++) { offs[e] = a; a += counts[e]; cursor[e] = 0; }
    offs[E_NUM] = a;                 // == 8192
    offs[E_NUM + 1] = a + T_TOK;     // shared slots 8192..12287
  }
}

__global__ void dispatch_kernel(const int* __restrict__ topidx,
                                const int* __restrict__ offs, int* __restrict__ cursor,
                                int* __restrict__ gidx, int* __restrict__ slot_of) {
  int t = blockIdx.x * blockDim.x + threadIdx.x;
  if (t >= T_TOK) return;
  #pragma unroll
  for (int j = 0; j < 2; j++) {
    int ex  = topidx[t * 2 + j];
    int pos = atomicAdd(&cursor[ex], 1);
    int slot = offs[ex] + pos;
    gidx[slot] = t;
    slot_of[t * 2 + j] = slot;
  }
}

// ---------------- GEMM 64x256, BK=64, 4 waves (1Mx4N), m97 single-buffer ----
// FINAL config (r18: 505us total, ~180us/GEMM). Why frozen:
// - 4x4 f32x4 acc (64 AGPR) + 64 VGPR = 128 unified regs/wave -> 16 waves/CU
//   register ceiling (m69) -> 4 blocks/CU is the HW-maximal co-residency for
//   this accumulator; measured alternatives all regress: dbuf@2blk (r11: 202us),
//   8-phase@1blk (r2: 294us), BM=128 (r10: 206us), grid swap (r13: 235us).
// - grid x=n-panel (fastest), y=m-tile, z=expert: consecutive ids share the A
//   tile; FETCH 296MB vs 450-460MB for other orderings.
// - launch_bounds (256,4): VGPR cap 128, no spill (r9: (512,6) spilled acc).
// - FFN1 z=9 slice transposes w2 -> wAll2 riding FFN1's idle memory pipe.
// r19/r20: FFN1's A is TOKEN-ORDER xb[4096][1024]; per-thread row pointer uses
// gidx[slot] (routed, CLAMPED to the expert's last valid slot -- r19 crashed
// on an unclamped tail read past gidx[8191] into poisoned workspace) /
// slot-8192 identity (shared) -> standalone gather eliminated.
// Per-wave output 64x64 (acc 4x4); all 4 waves share the A fragments.
// LDS rows of 64 bf16 (128B = 8x16B units), XOR swizzle u' = u ^ (row&7),
// staged via global_load_lds (linear dest, pre-swizzled global source).
// B columns permuted within each 64-group: LDS row r (rr=r&63) holds weight col
// n0 + (r&192) + 4*(rr&15) + (rr>>4) -> lane owns 4 adjacent cols -> coalesced stores.
template <bool FFN1>
__global__ __launch_bounds__(256, 4) void gemm64x256(
    const unsigned short* __restrict__ A,    // FFN1: xb [4096][1024]; else hdn [12288][4096]
    const unsigned short* __restrict__ Bt,   // wAll [9][N][K] (K-contig)
    const float* __restrict__ b_r,           // routed bias [8][N]
    const float* __restrict__ b_s,           // shared bias [N]
    unsigned short* __restrict__ outp,       // FFN1: hdn bf16; else y bf16
    const int* __restrict__ offs,            // [10]
    const int* __restrict__ gidx,            // FFN1: routed slot -> token (8192)
    const float* __restrict__ w2src,         // FFN1 fusion: w2 [8][FF][H] f32
    const float* __restrict__ sw2src,        // FFN1 fusion: sw2 [FF][H] f32
    unsigned short* __restrict__ w2t,        // FFN1 fusion: wAll2 [9][H][FF] bf16
    int K, int N) {
  __shared__ __align__(16) char ldsA[64 * 128];    //  8 KB
  __shared__ __align__(16) char ldsB[256 * 128];   // 32 KB

  // ---- fused w2 transpose slice (FFN1 only, z == 9) ----
  // x in [0,16): H/64 col-tiles; y in [0,64): FF/64 row-tiles
  if (FFN1 && blockIdx.z == E_NUM + 1) {
    float (*tile)[65] = (float (*)[65])ldsB;       // 16.6 KB, fits in ldsB
    const int c0 = blockIdx.x * 64;                // H cols
    const int r0 = blockIdx.y * 64;                // FF rows
    const int tx = threadIdx.x & 15, ty = threadIdx.x >> 4;
    for (int z2 = 0; z2 <= E_NUM; z2++) {
      const float* inb = (z2 < E_NUM) ? (w2src + (size_t)z2 * FF_DIM * H_DIM) : sw2src;
      unsigned short* outb = w2t + (size_t)z2 * FF_DIM * H_DIM;
      #pragma unroll
      for (int i = 0; i < 4; i++) {
        int row = ty + i * 16;
        float4 v = *(const float4*)(inb + (size_t)(r0 + row) * H_DIM + c0 + tx * 4);
        tile[row][tx * 4 + 0] = v.x;
        tile[row][tx * 4 + 1] = v.y;
        tile[row][tx * 4 + 2] = v.z;
        tile[row][tx * 4 + 3] = v.w;
      }
      __syncthreads();
      int rr0 = tx * 4;
      #pragma unroll
      for (int p = 0; p < 4; p++) {
        int col = p * 16 + ty;
        ushort4 o;
        o.x = f2bf(tile[rr0 + 0][col]);
        o.y = f2bf(tile[rr0 + 1][col]);
        o.z = f2bf(tile[rr0 + 2][col]);
        o.w = f2bf(tile[rr0 + 3][col]);
        *(ushort4*)(outb + (size_t)(c0 + col) * FF_DIM + r0 + rr0) = o;
      }
      __syncthreads();   // tile reused by next expert
    }
    return;
  }

  // ---- GEMM path (z in [0, 9)) ----
  const int e  = blockIdx.z;
  const int m0 = blockIdx.y * 64;
  const int cnt = offs[e + 1] - offs[e];
  if (m0 >= cnt) return;
  const int base  = offs[e] + m0;
  const int valid = min(64, cnt - m0);
  const int slotMax = offs[e] + cnt - 1;   // last valid slot for this expert
  const int n0 = blockIdx.x * 256;

  const int tid = threadIdx.x;
  const int l = tid & 63;

  // staging: per K-tile, A = 2 chunks/thread, B = 8 chunks/thread (16B each)
  const int srow = tid >> 3;               // 0..31 (+32j)
  const int su   = (tid & 7) ^ (srow & 7); // pre-swizzled source 16B-unit
  const unsigned short* aSrc[2];
  const unsigned short* bSrc[8];
  const unsigned short* BtE = Bt + (size_t)e * (size_t)N * (size_t)K;
  #pragma unroll
  for (int j = 0; j < 2; j++) {
    int slot = base + j * 32 + srow;       // A tile row 0..63 (slot index)
    size_t arow;
    if (FFN1) {
      // slot -> token: routed via gidx (clamped to this expert's last valid
      // slot: tail reads duplicate a legitimate row, never leave gidx bounds;
      // epilogue masks stores by `valid`). Shared (e==8): identity, exact count.
      int tok = (e < E_NUM) ? gidx[min(slot, slotMax)] : (slot - 2 * T_TOK);
      arow = (size_t)tok;
    } else {
      arow = (size_t)slot;                 // hdn is compact slot-order
    }
    aSrc[j] = A + arow * (size_t)K + su * 8;
  }
  #pragma unroll
  for (int j = 0; j < 8; j++) {
    int r = j * 32 + srow;                 // B tile row 0..255
    int rr = r & 63;
    int nr = n0 + (r & 192) + ((rr & 15) << 2) + (rr >> 4);   // col permutation
    bSrc[j] = BtE + (size_t)nr * (size_t)K + su * 8;
  }

  f32x4 acc[4][4];
  #pragma unroll
  for (int m = 0; m < 4; m++)
    #pragma unroll
    for (int n = 0; n < 4; n++) acc[m][n] = (f32x4){0.f, 0.f, 0.f, 0.f};

  const int wc = tid >> 6;                // wave 0..3 = N-group
  const int l15 = l & 15, l4 = l >> 4, l7 = l & 7;

  for (int kt = 0; kt < K; kt += 64) {
    #pragma unroll
    for (int j = 0; j < 2; j++)
      __builtin_amdgcn_global_load_lds((const AS1 void*)(aSrc[j] + kt),
                                       (AS3 void*)(ldsA + (j * 256 + tid) * 16), 16, 0, 0);
    #pragma unroll
    for (int j = 0; j < 8; j++)
      __builtin_amdgcn_global_load_lds((const AS1 void*)(bSrc[j] + kt),
                                       (AS3 void*)(ldsB + (j * 256 + tid) * 16), 16, 0, 0);
    __syncthreads();   // drains vmcnt before barrier
    #pragma unroll
    for (int kk = 0; kk < 2; kk++) {
      const int uoff = ((kk * 4 + l4) ^ l7) << 4;
      bf16x8 af[4], bfr[4];
      #pragma unroll
      for (int m = 0; m < 4; m++)
        af[m] = *(const bf16x8*)(ldsA + (m * 16 + l15) * 128 + uoff);
      #pragma unroll
      for (int n = 0; n < 4; n++)
        bfr[n] = *(const bf16x8*)(ldsB + (wc * 64 + n * 16 + l15) * 128 + uoff);
      #pragma unroll
      for (int m = 0; m < 4; m++)
        #pragma unroll
        for (int n = 0; n < 4; n++)
          acc[m][n] = __builtin_amdgcn_mfma_f32_16x16x32_bf16(af[m], bfr[n], acc[m][n], 0, 0, 0);
    }
    __syncthreads();
  }

  // epilogue: lane owns cols c0..c0+3 (B-permutation); C/D row = l4*4+j
  const float* bias = (e < E_NUM) ? (b_r + (size_t)e * N) : b_s;
  const int c0 = n0 + wc * 64 + 4 * l15;
  float4 bv = *(const float4*)(bias + c0);
  #pragma unroll
  for (int m = 0; m < 4; m++) {
    #pragma unroll
    for (int j = 0; j < 4; j++) {
      int rl = m * 16 + l4 * 4 + j;
      if (rl < valid) {
        ushort4 o;
        if (FFN1) {
          o.x = f2bf(gelu_f(acc[m][0][j] + bv.x));
          o.y = f2bf(gelu_f(acc[m][1][j] + bv.y));
          o.z = f2bf(gelu_f(acc[m][2][j] + bv.z));
          o.w = f2bf(gelu_f(acc[m][3][j] + bv.w));
        } else {
          o.x = f2bf(acc[m][0][j] + bv.x);
          o.y = f2bf(acc[m][1][j] + bv.y);
          o.z = f2bf(acc[m][2][j] + bv.z);
          o.w = f2bf(acc[m][3][j] + bv.w);
        }
        *(ushort4*)(outp + (size_t)(base + rl) * N + c0) = o;
      }
    }
  }
}

// out[t] = w1*y[s1] + w2*y[s2] + 0.1*y[8192+t]   (biases already in y; y bf16)
__global__ __launch_bounds__(256) void combine_kernel(
    const unsigned short* __restrict__ y, const float* __restrict__ topw,
    const int* __restrict__ slot_of, float* __restrict__ out) {
  int t = blockIdx.x;
  int g = threadIdx.x;
  int s1 = slot_of[2 * t], s2 = slot_of[2 * t + 1];
  float w1 = topw[2 * t], w2 = topw[2 * t + 1];
  ushort4 a = *(const ushort4*)(y + (size_t)s1 * H_DIM + g * 4);
  ushort4 b = *(const ushort4*)(y + (size_t)s2 * H_DIM + g * 4);
  ushort4 c = *(const ushort4*)(y + (size_t)(2 * T_TOK + t) * H_DIM + g * 4);
  float4 o;
  o.x = w1 * bf2f(a.x) + w2 * bf2f(b.x) + 0.1f * bf2f(c.x);
  o.y = w1 * bf2f(a.y) + w2 * bf2f(b.y) + 0.1f * bf2f(c.y);
  o.z = w1 * bf2f(a.z) + w2 * bf2f(b.z) + 0.1f * bf2f(c.z);
  o.w = w1 * bf2f(a.w) + w2 * bf2f(b.w) + 0.1f * bf2f(c.w);
  *(float4*)(out + (size_t)t * H_DIM + g * 4) = o;
}

// ---------------- host ----------------
extern "C" void kernel_launch(void* const* d_in, const int* in_sizes, int n_in,
                              void* d_out, int out_size, void* d_ws, size_t ws_size,
                              hipStream_t stream) {
  const float* x   = (const float*)d_in[0];
  const float* gw  = (const float*)d_in[1];
  const float* gb  = (const float*)d_in[2];
  const float* w1  = (const float*)d_in[3];
  const float* b1  = (const float*)d_in[4];
  const float* w2  = (const float*)d_in[5];
  const float* b2  = (const float*)d_in[6];
  const float* sw1 = (const float*)d_in[7];
  const float* sb1 = (const float*)d_in[8];
  const float* sw2 = (const float*)d_in[9];
  const float* sb2 = (const float*)d_in[10];
  float* out = (float*)d_out;

  char* p = (char*)d_ws;
  auto alloc = [&](size_t bytes) {
    char* r = p;
    p += (bytes + 255) & ~(size_t)255;
    return r;
  };
  int*   counts  = (int*)alloc(E_NUM * 4);
  int*   cursor  = (int*)alloc(E_NUM * 4);
  int*   offs    = (int*)alloc((E_NUM + 2) * 4);
  int*   topidx  = (int*)alloc((size_t)T_TOK * 2 * 4);
  float* topw    = (float*)alloc((size_t)T_TOK * 2 * 4);
  int*   slot_of = (int*)alloc((size_t)T_TOK * 2 * 4);
  int*   gidx    = (int*)alloc((size_t)2 * T_TOK * 4);
  unsigned short* xb    = (unsigned short*)alloc((size_t)T_TOK * H_DIM * 2);       //  8 MB
  unsigned short* wAll1 = (unsigned short*)alloc((size_t)(E_NUM + 1) * FF_DIM * H_DIM * 2);  // 72 MB
  unsigned short* wAll2 = (unsigned short*)alloc((size_t)(E_NUM + 1) * FF_DIM * H_DIM * 2);  // 72 MB
  unsigned short* hdn   = (unsigned short*)alloc((size_t)3 * T_TOK * FF_DIM * 2);  // 96 MB
  unsigned short* yb    = (unsigned short*)alloc((size_t)3 * T_TOK * H_DIM * 2);   // 24 MB

  // counts zeroed via memset node
  hipMemsetAsync(counts, 0, E_NUM * 4, stream);

  // FUSED gate (writes xb token rows) + w1 transpose (both dependency-free)
  gate_w1t_kernel<<<GATE_BLOCKS + W1T_BLOCKS, 256, 0, stream>>>(
      x, gw, gb, topidx, topw, counts, xb, w1, sw1, wAll1);
  scan_kernel<<<1, 1, 0, stream>>>(counts, offs, cursor);
  dispatch_kernel<<<T_TOK / 256, 256, 0, stream>>>(topidx, offs, cursor, gidx, slot_of);

  // FFN1 GEMM (A gathered from xb via gidx during staging) + fused w2 transpose
  gemm64x256<true><<<dim3(FF_DIM / 256, T_TOK / 64, E_NUM + 2), 256, 0, stream>>>(
      xb, wAll1, b1, sb1, hdn, offs, gidx, w2, sw2, wAll2, H_DIM, FF_DIM);

  // FFN2 GEMM (grid: x=n-panels, y=m-tiles)
  gemm64x256<false><<<dim3(H_DIM / 256, T_TOK / 64, E_NUM + 1), 256, 0, stream>>>(
      hdn, wAll2, b2, sb2, yb, offs, nullptr, nullptr, nullptr, nullptr, FF_DIM, H_DIM);

  // weighted combine (routed top-2 + 0.1 * shared)
  combine_kernel<<<T_TOK, 256, 0, stream>>>(yb, topw, slot_of, out);
}